// Round 5
// baseline (723.912 us; speedup 1.0000x reference)
//
#include <hip/hip_runtime.h>
#include <math.h>

#define NS 4096

typedef _Float16 half8 __attribute__((ext_vector_type(8)));
typedef _Float16 half2v __attribute__((ext_vector_type(2)));
typedef float floatx16 __attribute__((ext_vector_type(16)));

// ---------------- LDS layout (f32 offsets), main kernel ----------------
// xc  : 8 shift-copies of f16 padded input, stride 648 f16
// p1T : [260 pos][72 f16]  (64 ch data; 36 words == 4 mod 32 -> conflict-free b128)
// p2T : [130 pos][136 f16] (128 ch data; 68 words == 4 mod 32)
// scr : feat[256]@0, h[128]@256, zsq[128]@384 ; scr2[1024] = per-ch 4 partial sums
#define XC_OFF      0
#define XC_STRIDE   648
#define P1T_OFF     2592
#define P1T_STRIDE  72
#define P2T_OFF     11952
#define P2T_STRIDE  136
#define SCR_OFF     20792
#define SCR2_OFF    21304
#define B1_OFF      22328
#define B2_OFF      22392
#define B3_OFF      22520
#define LDS_MAIN_FLOATS 22776   // 91,104 B -> 1 block/CU

// ---------------- weight prep: f32 -> f16 MFMA layouts ----------------
// w1p[64 m][128 k] (k<100 real, else 0); w2p[5][128 m][64 i]; w3p[3][256 m][128 i]
__global__ void prep_weights(const float* __restrict__ w1,
                             const float* __restrict__ w2,
                             const float* __restrict__ w3,
                             _Float16* __restrict__ w1p,
                             _Float16* __restrict__ w2p,
                             _Float16* __restrict__ w3p)
{
    int gid = blockIdx.x * 256 + threadIdx.x;
    if (gid < 8192) {
        int m = gid >> 7, k = gid & 127;
        w1p[gid] = (k < 100) ? (_Float16)w1[m * 100 + k] : (_Float16)0.f;
    } else if (gid < 49152) {
        int r = gid - 8192;
        int dk = r >> 13, rem = r & 8191;
        int m = rem >> 6, i = rem & 63;
        w2p[r] = (_Float16)w2[(m * 64 + i) * 5 + dk];
    } else if (gid < 147456) {
        int r = gid - 49152;
        int dk = r >> 15, rem = r & 32767;
        int m = rem >> 7, i = rem & 127;
        w3p[r] = (_Float16)w3[(m * 128 + i) * 3 + dk];
    }
}

// inclusive add-scan within each 16-lane row via DPP row_shr; lane (l%16)==15 holds row sum
__device__ __forceinline__ float dpp_rowsum16(float v) {
    int x;
    x = __builtin_amdgcn_update_dpp(0, __float_as_int(v), 0x111, 0xF, 0xF, true);
    v += __int_as_float(x);
    x = __builtin_amdgcn_update_dpp(0, __float_as_int(v), 0x112, 0xF, 0xF, true);
    v += __int_as_float(x);
    x = __builtin_amdgcn_update_dpp(0, __float_as_int(v), 0x114, 0xF, 0xF, true);
    v += __int_as_float(x);
    x = __builtin_amdgcn_update_dpp(0, __float_as_int(v), 0x118, 0xF, 0xF, true);
    v += __int_as_float(x);
    return v;
}

// C/D 32x32 layout: col = lane&31, row = (reg&3) + 8*(reg>>2) + 4*(lane>>5)
// A/B layout: m|n = lane&31, k = (lane>>5)*8 + j (+16*kb)

__global__ __launch_bounds__(512, 2)
void cnn_fused(const float* __restrict__ samples, const int* __restrict__ info,
               const _Float16* __restrict__ w1p,
               const _Float16* __restrict__ w2p,
               const _Float16* __restrict__ w3p,
               const float* __restrict__ b1, const float* __restrict__ b2,
               const float* __restrict__ b3,
               const float* __restrict__ fcw, const float* __restrict__ fcb,
               const float* __restrict__ gamma_, const float* __restrict__ beta_,
               const float* __restrict__ bnm, const float* __restrict__ bnv,
               _Float16* __restrict__ zh, float* __restrict__ sqout,
               int* __restrict__ uout)
{
    extern __shared__ float lds[];
    _Float16* xc  = (_Float16*)(lds + XC_OFF);
    _Float16* p1T = (_Float16*)(lds + P1T_OFF);
    _Float16* p2T = (_Float16*)(lds + P2T_OFF);

    const int n    = blockIdx.x;
    const int t    = threadIdx.x;
    const int lane = t & 63;
    const int wave = t >> 6;
    const int g    = lane >> 5;
    const int col  = lane & 31;

    // ---- stage: xc[c][u] = x[u + c - 49] as f16 (8 shifted copies for aligned b128)
    for (int i = t; i < 8 * XC_STRIDE; i += 512) {
        int c = i / XC_STRIDE;
        int u = i - c * XC_STRIDE;
        int src = u + c - 49;
        xc[i] = (_Float16)((src >= 0 && src < 512) ? samples[n * 512 + src] : 0.f);
    }
    // ---- biases to LDS
    if (t < 64)              lds[B1_OFF + t] = b1[t];
    if (t >= 64 && t < 192)  lds[B2_OFF + (t - 64)] = b2[t - 64];
    if (t >= 192 && t < 448) lds[B3_OFF + (t - 192)] = b3[t - 192];
    // ---- zero halos: p1T rows {0,1,258,259} (36 f32 each), p2T rows {0,129} (68 f32)
    if (t < 144) {
        int rr = t / 36, c4 = t - rr * 36;
        int row = (rr < 2) ? rr : (256 + rr);
        lds[P1T_OFF + row * 36 + c4] = 0.f;
    } else if (t < 280) {
        int i2 = t - 144;
        int row = (i2 < 68) ? 0 : 129;
        int c4 = (i2 < 68) ? i2 : (i2 - 68);
        lds[P2T_OFF + row * 68 + c4] = 0.f;
    }
    __syncthreads();

    // pooled relu store: vm duplicated in lane pairs; even lanes write f16 transposed
    auto pool_store = [&](floatx16& acc, _Float16* dst) {
        float vm[16];
        #pragma unroll
        for (int r = 0; r < 16; ++r) {
            float v = fmaxf(acc[r], 0.f);
            vm[r] = fmaxf(v, __shfl_xor(v, 1));
        }
        if (!(lane & 1)) {
            #pragma unroll
            for (int rq = 0; rq < 4; ++rq) {
                half2v p0, p1;
                p0[0] = (_Float16)vm[4 * rq];     p0[1] = (_Float16)vm[4 * rq + 1];
                p1[0] = (_Float16)vm[4 * rq + 2]; p1[1] = (_Float16)vm[4 * rq + 3];
                *(half2v*)(dst + 8 * rq)     = p0;
                *(half2v*)(dst + 8 * rq + 2) = p1;
            }
        }
    };

    // ============ conv1: M=64 (2 mt/wave), N=512 (2 nt/wave), K=128 ============
    {
        half8 A[2][8];
        #pragma unroll
        for (int mt = 0; mt < 2; ++mt)
            #pragma unroll
            for (int kb = 0; kb < 8; ++kb)
                A[mt][kb] = *(const half8*)(w1p + (mt * 32 + col) * 128 + kb * 16 + g * 8);
        float bv0[16], bv1[16];
        #pragma unroll
        for (int r = 0; r < 16; ++r) {
            int rm = (r & 3) + 8 * (r >> 2) + 4 * g;
            bv0[r] = lds[B1_OFF + rm];
            bv1[r] = lds[B1_OFF + 32 + rm];
        }
        #pragma unroll
        for (int s = 0; s < 2; ++s) {
            const int nt = wave * 2 + s;
            const int nn = nt * 32 + col;
            const int c  = nn & 7;
            const _Float16* xcp = xc + c * XC_STRIDE + (nn - c) + g * 8;
            floatx16 a0, a1;
            #pragma unroll
            for (int r = 0; r < 16; ++r) { a0[r] = bv0[r]; a1[r] = bv1[r]; }
            #pragma unroll
            for (int kb = 0; kb < 8; ++kb) {
                half8 B = *(const half8*)(xcp + kb * 16);
                a0 = __builtin_amdgcn_mfma_f32_32x32x16_f16(A[0][kb], B, a0, 0, 0, 0);
                a1 = __builtin_amdgcn_mfma_f32_32x32x16_f16(A[1][kb], B, a1, 0, 0, 0);
            }
            const int P = 2 + nt * 16 + (col >> 1);
            pool_store(a0, p1T + P * P1T_STRIDE + 4 * g);
            pool_store(a1, p1T + P * P1T_STRIDE + 32 + 4 * g);
        }
    }
    __syncthreads();

    // ============ conv2: M=128 (2 mt/wave), N=256 (2 nt/wave), K=5x64 ============
    {
        const int mtb = (wave & 1) * 2;
        const int ntb = (wave >> 1) * 2;
        floatx16 acc[2][2];
        #pragma unroll
        for (int mt = 0; mt < 2; ++mt)
            #pragma unroll
            for (int r = 0; r < 16; ++r) {
                float bv = lds[B2_OFF + (mtb + mt) * 32 + (r & 3) + 8 * (r >> 2) + 4 * g];
                acc[mt][0][r] = bv; acc[mt][1][r] = bv;
            }
        #pragma unroll
        for (int dk = 0; dk < 5; ++dk) {
            half8 A[2][4];
            #pragma unroll
            for (int mt = 0; mt < 2; ++mt)
                #pragma unroll
                for (int kb = 0; kb < 4; ++kb)
                    A[mt][kb] = *(const half8*)(w2p + (dk * 128 + (mtb + mt) * 32 + col) * 64 + kb * 16 + g * 8);
            #pragma unroll
            for (int s = 0; s < 2; ++s) {
                const int row = (ntb + s) * 32 + col + dk;
                const _Float16* bp = p1T + row * P1T_STRIDE + g * 8;
                #pragma unroll
                for (int kb = 0; kb < 4; ++kb) {
                    half8 B = *(const half8*)(bp + kb * 16);
                    acc[0][s] = __builtin_amdgcn_mfma_f32_32x32x16_f16(A[0][kb], B, acc[0][s], 0, 0, 0);
                    acc[1][s] = __builtin_amdgcn_mfma_f32_32x32x16_f16(A[1][kb], B, acc[1][s], 0, 0, 0);
                }
            }
        }
        #pragma unroll
        for (int s = 0; s < 2; ++s) {
            const int P = 1 + (ntb + s) * 16 + (col >> 1);
            pool_store(acc[0][s], p2T + P * P2T_STRIDE + mtb * 32 + 4 * g);
            pool_store(acc[1][s], p2T + P * P2T_STRIDE + (mtb + 1) * 32 + 4 * g);
        }
    }
    __syncthreads();

    // ============ conv3: M=256 (2 mt/wave), N=128 (2 nt/wave), K=3x128; fused pool+mean partials ============
    {
        const int mtb = (wave & 3) * 2;
        const int wg  = wave >> 2;
        const int ntb = wg * 2;
        floatx16 acc[2][2];
        #pragma unroll
        for (int mt = 0; mt < 2; ++mt)
            #pragma unroll
            for (int r = 0; r < 16; ++r) {
                float bv = lds[B3_OFF + (mtb + mt) * 32 + (r & 3) + 8 * (r >> 2) + 4 * g];
                acc[mt][0][r] = bv; acc[mt][1][r] = bv;
            }
        #pragma unroll
        for (int dk = 0; dk < 3; ++dk) {
            half8 A[2][8];
            #pragma unroll
            for (int mt = 0; mt < 2; ++mt)
                #pragma unroll
                for (int kb = 0; kb < 8; ++kb)
                    A[mt][kb] = *(const half8*)(w3p + (dk * 256 + (mtb + mt) * 32 + col) * 128 + kb * 16 + g * 8);
            #pragma unroll
            for (int s = 0; s < 2; ++s) {
                const int row = (ntb + s) * 32 + col + dk;
                const _Float16* bp = p2T + row * P2T_STRIDE + g * 8;
                #pragma unroll
                for (int kb = 0; kb < 8; ++kb) {
                    half8 B = *(const half8*)(bp + kb * 16);
                    acc[0][s] = __builtin_amdgcn_mfma_f32_32x32x16_f16(A[0][kb], B, acc[0][s], 0, 0, 0);
                    acc[1][s] = __builtin_amdgcn_mfma_f32_32x32x16_f16(A[1][kb], B, acc[1][s], 0, 0, 0);
                }
            }
        }
        // relu + pool(xor1, duplicated) + row-sum(DPP) -> 4 partials per channel
        const int q = wg * 2 + ((lane >> 4) & 1);
        #pragma unroll
        for (int mt = 0; mt < 2; ++mt) {
            float red[16];
            #pragma unroll
            for (int r = 0; r < 16; ++r) {
                float sum = 0.f;
                #pragma unroll
                for (int s = 0; s < 2; ++s) {
                    float v = fmaxf(acc[mt][s][r], 0.f);
                    sum += fmaxf(v, __shfl_xor(v, 1));
                }
                red[r] = dpp_rowsum16(sum);
            }
            if ((lane & 15) == 15) {
                #pragma unroll
                for (int r = 0; r < 16; ++r) {
                    int ch = (mtb + mt) * 32 + (r & 3) + 8 * (r >> 2) + 4 * g;
                    lds[SCR2_OFF + ch * 4 + q] = red[r];
                }
            }
        }
    }
    __syncthreads();

    // ---- mean: 4 partials each count pooled values twice -> /128
    if (t < 256) {
        const float4 qv = *(const float4*)&lds[SCR2_OFF + t * 4];
        lds[SCR_OFF + t] = (qv.x + qv.y + qv.z + qv.w) * (1.f / 128.f);
    }
    __syncthreads();

    // ---- fc (256->128) + relu
    {
        for (int ow = 0; ow < 16; ++ow) {
            const int o = wave * 16 + ow;
            float s = 0.f;
            #pragma unroll
            for (int m = 0; m < 4; ++m) {
                int i = lane + 64 * m;
                s += fcw[o * 256 + i] * lds[SCR_OFF + i];
            }
            #pragma unroll
            for (int off = 32; off > 0; off >>= 1) s += __shfl_down(s, off);
            if (lane == 0) lds[SCR_OFF + 256 + o] = fmaxf(s + fcb[o], 0.f);
        }
    }
    __syncthreads();

    // ---- batchnorm -> z (f16); CONSISTENCY: sq computed from the QUANTIZED z so
    //      d2 = ||zq_i||^2 + ||zq_j||^2 - 2<zq_i,zq_j> is a true squared distance.
    if (t < 128) {
        float hv = lds[SCR_OFF + 256 + t];
        float zv = gamma_[t] * (hv - bnm[t]) * (1.f / sqrtf(bnv[t] + 1e-5f)) + beta_[t];
        _Float16 zq = (_Float16)zv;
        zh[(size_t)n * 128 + t] = zq;
        float zqf = (float)zq;
        lds[SCR_OFF + 384 + t] = zqf * zqf;
    }
    if (t == 0) uout[n] = (info[2 * n + 1] == 1) ? info[2 * n] : -1;
    __syncthreads();
    if (t < 64) {
        float s = lds[SCR_OFF + 384 + t] + lds[SCR_OFF + 384 + 64 + t];
        #pragma unroll
        for (int off = 32; off > 0; off >>= 1) s += __shfl_down(s, off);
        if (t == 0) sqout[n] = s;
    }
}

// ---- pairwise via f16 MFMA: 128x128 tile/block, 4 waves, each 64x64 quadrant
#define PW_STRIDE 136   // f16; 68 words == 4 mod 32 -> conflict-free b128
#define PW_LDS_BYTES (2 * 128 * PW_STRIDE * 2)

__global__ __launch_bounds__(256, 2)
void pairwise_mfma(const _Float16* __restrict__ zh, const float* __restrict__ sq,
                   const int* __restrict__ u, float* __restrict__ out)
{
    extern __shared__ float ldsf[];
    _Float16* at = (_Float16*)ldsf;                  // [128][136]
    _Float16* bt = at + 128 * PW_STRIDE;
    const int t = threadIdx.x;
    const int i0 = blockIdx.y * 128;
    const int j0 = blockIdx.x * 128;

    #pragma unroll
    for (int r4 = 0; r4 < 8; ++r4) {
        int idx = t + 256 * r4;            // 0..2047
        int row = idx >> 4, c8 = (idx & 15) * 8;
        *(half8*)(at + row * PW_STRIDE + c8) = *(const half8*)(zh + (size_t)(i0 + row) * 128 + c8);
        *(half8*)(bt + row * PW_STRIDE + c8) = *(const half8*)(zh + (size_t)(j0 + row) * 128 + c8);
    }
    __syncthreads();

    const int lane = t & 63, wave = t >> 6;
    const int g = lane >> 5, col = lane & 31;
    const int ib = (wave & 1) * 64, jb = (wave >> 1) * 64;

    half8 A[2][8];
    #pragma unroll
    for (int mt = 0; mt < 2; ++mt)
        #pragma unroll
        for (int kb = 0; kb < 8; ++kb)
            A[mt][kb] = *(const half8*)(at + (ib + mt * 32 + col) * PW_STRIDE + kb * 16 + g * 8);

    floatx16 acc[2][2];
    #pragma unroll
    for (int a = 0; a < 2; ++a)
        #pragma unroll
        for (int b = 0; b < 2; ++b)
            #pragma unroll
            for (int r = 0; r < 16; ++r) acc[a][b][r] = 0.f;

    #pragma unroll
    for (int nt = 0; nt < 2; ++nt)
        #pragma unroll
        for (int kb = 0; kb < 8; ++kb) {
            half8 B = *(const half8*)(bt + (jb + nt * 32 + col) * PW_STRIDE + kb * 16 + g * 8);
            acc[0][nt] = __builtin_amdgcn_mfma_f32_32x32x16_f16(A[0][kb], B, acc[0][nt], 0, 0, 0);
            acc[1][nt] = __builtin_amdgcn_mfma_f32_32x32x16_f16(A[1][kb], B, acc[1][nt], 0, 0, 0);
        }

    #pragma unroll
    for (int nt = 0; nt < 2; ++nt) {
        const int j = j0 + jb + nt * 32 + col;
        const float sqj = sq[j];
        const int uj = u[j];
        #pragma unroll
        for (int mt = 0; mt < 2; ++mt) {
            #pragma unroll
            for (int r = 0; r < 16; ++r) {
                const int i = i0 + ib + mt * 32 + (r & 3) + 8 * (r >> 2) + 4 * g;
                float res;
                if (i == j) {
                    res = 0.f;
                } else {
                    float d2 = sq[i] + sqj - 2.f * acc[mt][nt][r];
                    float d = sqrtf(fmaxf(d2, 0.f));
                    int ui = u[i];
                    res = (ui == uj && ui >= 0) ? d : fmaxf(1.f - d, 0.f);
                }
                out[(size_t)i * 4096 + j] = res;
            }
        }
    }
}

extern "C" void kernel_launch(void* const* d_in, const int* in_sizes, int n_in,
                              void* d_out, int out_size, void* d_ws, size_t ws_size,
                              hipStream_t stream)
{
    const float* samples = (const float*)d_in[0];
    const int*   info    = (const int*)d_in[1];
    const float* w1  = (const float*)d_in[2];
    const float* b1  = (const float*)d_in[3];
    const float* w2  = (const float*)d_in[4];
    const float* b2  = (const float*)d_in[5];
    const float* w3  = (const float*)d_in[6];
    const float* b3  = (const float*)d_in[7];
    const float* fcw = (const float*)d_in[8];
    const float* fcb = (const float*)d_in[9];
    const float* g   = (const float*)d_in[10];
    const float* be  = (const float*)d_in[11];
    const float* bm  = (const float*)d_in[12];
    const float* bv  = (const float*)d_in[13];
    float* out = (float*)d_out;

    // ws: zh f16 [4096*128] @0 (1 MB); sq f32 @1MB (16 KB); u int @1MB+16K (16 KB);
    //     w1p/w2p/w3p f16 @1MB+32K
    _Float16* zhws = (_Float16*)d_ws;
    float*    sqws = (float*)((char*)d_ws + (1 << 20));
    int*      uws  = (int*)((char*)d_ws + (1 << 20) + 16384);
    _Float16* wp   = (_Float16*)((char*)d_ws + (1 << 20) + 32768);
    _Float16* w1p = wp;               // 8192
    _Float16* w2p = wp + 8192;        // 40960
    _Float16* w3p = wp + 49152;       // 98304

    hipLaunchKernelGGL(prep_weights, dim3(576), dim3(256), 0, stream,
                       w1, w2, w3, w1p, w2p, w3p);

    hipLaunchKernelGGL(cnn_fused, dim3(NS), dim3(512),
                       LDS_MAIN_FLOATS * sizeof(float), stream,
                       samples, info, w1p, w2p, w3p, b1, b2, b3, fcw, fcb,
                       g, be, bm, bv, zhws, sqws, uws);

    hipLaunchKernelGGL(pairwise_mfma, dim3(32, 32), dim3(256),
                       PW_LDS_BYTES, stream,
                       zhws, sqws, uws, out);
}

// Round 6
// 614.840 us; speedup vs baseline: 1.1774x; 1.1774x over previous
//
#include <hip/hip_runtime.h>
#include <math.h>

#define NS 4096

typedef _Float16 half8 __attribute__((ext_vector_type(8)));
typedef _Float16 half2v __attribute__((ext_vector_type(2)));
typedef float floatx16 __attribute__((ext_vector_type(16)));

// ---------------- LDS layout (f32 word offsets), main kernel ----------------
// Aliased regions (liveness-disjoint):
//   p1T [260][72 f16] @0          (9360 f32)  -- conv1 out / conv2 in; dead after conv2
//     scr2[1024] @0, scr[512] @1024           -- written conv3-epilogue and later
//   p2T [130][136 f16] @9360      (8840 f32)  -- conv2 out / conv3 in
//     xc 8x648 f16 @9360          (2592 f32)  -- staging + conv1 in; dead after conv1
//   biases @18200 (448 f32)
#define P1T_OFF     0
#define P1T_STRIDE  72
#define P2T_OFF     9360
#define P2T_STRIDE  136
#define XC_OFF      9360
#define XC_STRIDE   648
#define SCR2_OFF    0
#define SCR_OFF     1024
#define B1_OFF      18200
#define B2_OFF      18264
#define B3_OFF      18392
#define LDS_MAIN_FLOATS 18648   // 74,592 B -> 2 blocks/CU

// ---------------- weight prep: f32 -> f16 MFMA layouts ----------------
// w1p[64 m][128 k] (k<100 real, else 0); w2p[5][128 m][64 i]; w3p[3][256 m][128 i]
__global__ void prep_weights(const float* __restrict__ w1,
                             const float* __restrict__ w2,
                             const float* __restrict__ w3,
                             _Float16* __restrict__ w1p,
                             _Float16* __restrict__ w2p,
                             _Float16* __restrict__ w3p)
{
    int gid = blockIdx.x * 256 + threadIdx.x;
    if (gid < 8192) {
        int m = gid >> 7, k = gid & 127;
        w1p[gid] = (k < 100) ? (_Float16)w1[m * 100 + k] : (_Float16)0.f;
    } else if (gid < 49152) {
        int r = gid - 8192;
        int dk = r >> 13, rem = r & 8191;
        int m = rem >> 6, i = rem & 63;
        w2p[r] = (_Float16)w2[(m * 64 + i) * 5 + dk];
    } else if (gid < 147456) {
        int r = gid - 49152;
        int dk = r >> 15, rem = r & 32767;
        int m = rem >> 7, i = rem & 127;
        w3p[r] = (_Float16)w3[(m * 128 + i) * 3 + dk];
    }
}

// inclusive add-scan within each 16-lane row via DPP row_shr; lane (l%16)==15 holds row sum
__device__ __forceinline__ float dpp_rowsum16(float v) {
    int x;
    x = __builtin_amdgcn_update_dpp(0, __float_as_int(v), 0x111, 0xF, 0xF, true);
    v += __int_as_float(x);
    x = __builtin_amdgcn_update_dpp(0, __float_as_int(v), 0x112, 0xF, 0xF, true);
    v += __int_as_float(x);
    x = __builtin_amdgcn_update_dpp(0, __float_as_int(v), 0x114, 0xF, 0xF, true);
    v += __int_as_float(x);
    x = __builtin_amdgcn_update_dpp(0, __float_as_int(v), 0x118, 0xF, 0xF, true);
    v += __int_as_float(x);
    return v;
}

// C/D 32x32 layout: col = lane&31, row = (reg&3) + 8*(reg>>2) + 4*(lane>>5)
// A/B layout: m|n = lane&31, k = (lane>>5)*8 + j (+16*kb)

__global__ __launch_bounds__(512, 4)
void cnn_fused(const float* __restrict__ samples, const int* __restrict__ info,
               const _Float16* __restrict__ w1p,
               const _Float16* __restrict__ w2p,
               const _Float16* __restrict__ w3p,
               const float* __restrict__ b1, const float* __restrict__ b2,
               const float* __restrict__ b3,
               const float* __restrict__ fcw, const float* __restrict__ fcb,
               const float* __restrict__ gamma_, const float* __restrict__ beta_,
               const float* __restrict__ bnm, const float* __restrict__ bnv,
               _Float16* __restrict__ zh, float* __restrict__ sqout,
               int* __restrict__ uout)
{
    extern __shared__ float lds[];
    _Float16* p1T = (_Float16*)(lds + P1T_OFF);
    _Float16* p2T = (_Float16*)(lds + P2T_OFF);
    _Float16* xc  = (_Float16*)(lds + XC_OFF);     // aliases p2T (dead after conv1)

    const int n    = blockIdx.x;
    const int t    = threadIdx.x;
    const int lane = t & 63;
    const int wave = t >> 6;
    const int g    = lane >> 5;
    const int col  = lane & 31;

    // ---- stage: xc[c][u] = x[u + c - 49] as f16 (8 shifted copies for aligned b128)
    for (int i = t; i < 8 * XC_STRIDE; i += 512) {
        int c = i / XC_STRIDE;
        int u = i - c * XC_STRIDE;
        int src = u + c - 49;
        xc[i] = (_Float16)((src >= 0 && src < 512) ? samples[n * 512 + src] : 0.f);
    }
    // ---- biases to LDS
    if (t < 64)              lds[B1_OFF + t] = b1[t];
    if (t >= 64 && t < 192)  lds[B2_OFF + (t - 64)] = b2[t - 64];
    if (t >= 192 && t < 448) lds[B3_OFF + (t - 192)] = b3[t - 192];
    // ---- zero p1T halos: rows {0,1,258,259} (36 f32 each). (p2T halos zeroed in conv2
    //      phase because xc aliases that region during staging/conv1.)
    if (t < 144) {
        int rr = t / 36, c4 = t - rr * 36;
        int row = (rr < 2) ? rr : (256 + rr);
        lds[P1T_OFF + row * 36 + c4] = 0.f;
    }
    __syncthreads();

    // pooled relu store: vm duplicated in lane pairs; even lanes write f16 transposed
    auto pool_store = [&](floatx16& acc, _Float16* dst) {
        float vm[16];
        #pragma unroll
        for (int r = 0; r < 16; ++r) {
            float v = fmaxf(acc[r], 0.f);
            vm[r] = fmaxf(v, __shfl_xor(v, 1));
        }
        if (!(lane & 1)) {
            #pragma unroll
            for (int rq = 0; rq < 4; ++rq) {
                half2v p0, p1;
                p0[0] = (_Float16)vm[4 * rq];     p0[1] = (_Float16)vm[4 * rq + 1];
                p1[0] = (_Float16)vm[4 * rq + 2]; p1[1] = (_Float16)vm[4 * rq + 3];
                *(half2v*)(dst + 8 * rq)     = p0;
                *(half2v*)(dst + 8 * rq + 2) = p1;
            }
        }
    };

    // ============ conv1: M=64 (2 mt/wave), N=512 (2 nt/wave), K=128 ============
    {
        half8 A[2][8];
        #pragma unroll
        for (int mt = 0; mt < 2; ++mt)
            #pragma unroll
            for (int kb = 0; kb < 8; ++kb)
                A[mt][kb] = *(const half8*)(w1p + (mt * 32 + col) * 128 + kb * 16 + g * 8);
        float bv0[16], bv1[16];
        #pragma unroll
        for (int r = 0; r < 16; ++r) {
            int rm = (r & 3) + 8 * (r >> 2) + 4 * g;
            bv0[r] = lds[B1_OFF + rm];
            bv1[r] = lds[B1_OFF + 32 + rm];
        }
        #pragma unroll
        for (int s = 0; s < 2; ++s) {
            const int nt = wave * 2 + s;
            const int nn = nt * 32 + col;
            const int c  = nn & 7;
            const _Float16* xcp = xc + c * XC_STRIDE + (nn - c) + g * 8;
            floatx16 a0, a1;
            #pragma unroll
            for (int r = 0; r < 16; ++r) { a0[r] = bv0[r]; a1[r] = bv1[r]; }
            #pragma unroll
            for (int kb = 0; kb < 8; ++kb) {
                half8 B = *(const half8*)(xcp + kb * 16);
                a0 = __builtin_amdgcn_mfma_f32_32x32x16_f16(A[0][kb], B, a0, 0, 0, 0);
                a1 = __builtin_amdgcn_mfma_f32_32x32x16_f16(A[1][kb], B, a1, 0, 0, 0);
            }
            const int P = 2 + nt * 16 + (col >> 1);
            pool_store(a0, p1T + P * P1T_STRIDE + 4 * g);
            pool_store(a1, p1T + P * P1T_STRIDE + 32 + 4 * g);
        }
    }
    __syncthreads();

    // ============ conv2: M=128 (2 mt/wave), N=256 (2 nt/wave), K=5x64 ============
    {
        // zero p2T halo rows {0,129} now that xc (aliased) is dead
        if (t < 136) {
            int row = (t < 68) ? 0 : 129;
            int c4 = (t < 68) ? t : (t - 68);
            lds[P2T_OFF + row * 68 + c4] = 0.f;
        }
        const int mtb = (wave & 1) * 2;
        const int ntb = (wave >> 1) * 2;
        floatx16 acc[2][2];
        #pragma unroll
        for (int mt = 0; mt < 2; ++mt)
            #pragma unroll
            for (int r = 0; r < 16; ++r) {
                float bv = lds[B2_OFF + (mtb + mt) * 32 + (r & 3) + 8 * (r >> 2) + 4 * g];
                acc[mt][0][r] = bv; acc[mt][1][r] = bv;
            }
        #pragma unroll
        for (int dk = 0; dk < 5; ++dk) {
            half8 A[2][4];
            #pragma unroll
            for (int mt = 0; mt < 2; ++mt)
                #pragma unroll
                for (int kb = 0; kb < 4; ++kb)
                    A[mt][kb] = *(const half8*)(w2p + (dk * 128 + (mtb + mt) * 32 + col) * 64 + kb * 16 + g * 8);
            #pragma unroll
            for (int s = 0; s < 2; ++s) {
                const int row = (ntb + s) * 32 + col + dk;
                const _Float16* bp = p1T + row * P1T_STRIDE + g * 8;
                #pragma unroll
                for (int kb = 0; kb < 4; ++kb) {
                    half8 B = *(const half8*)(bp + kb * 16);
                    acc[0][s] = __builtin_amdgcn_mfma_f32_32x32x16_f16(A[0][kb], B, acc[0][s], 0, 0, 0);
                    acc[1][s] = __builtin_amdgcn_mfma_f32_32x32x16_f16(A[1][kb], B, acc[1][s], 0, 0, 0);
                }
            }
        }
        #pragma unroll
        for (int s = 0; s < 2; ++s) {
            const int P = 1 + (ntb + s) * 16 + (col >> 1);
            pool_store(acc[0][s], p2T + P * P2T_STRIDE + mtb * 32 + 4 * g);
            pool_store(acc[1][s], p2T + P * P2T_STRIDE + (mtb + 1) * 32 + 4 * g);
        }
    }
    __syncthreads();

    // ============ conv3: M=256 (2 mt/wave), N=128 (2 nt/wave), K=3x128; fused pool+mean partials ============
    {
        const int mtb = (wave & 3) * 2;
        const int wg  = wave >> 2;
        const int ntb = wg * 2;
        floatx16 acc[2][2];
        #pragma unroll
        for (int mt = 0; mt < 2; ++mt)
            #pragma unroll
            for (int r = 0; r < 16; ++r) {
                float bv = lds[B3_OFF + (mtb + mt) * 32 + (r & 3) + 8 * (r >> 2) + 4 * g];
                acc[mt][0][r] = bv; acc[mt][1][r] = bv;
            }
        #pragma unroll
        for (int dk = 0; dk < 3; ++dk) {
            half8 A[2][8];
            #pragma unroll
            for (int mt = 0; mt < 2; ++mt)
                #pragma unroll
                for (int kb = 0; kb < 8; ++kb)
                    A[mt][kb] = *(const half8*)(w3p + (dk * 256 + (mtb + mt) * 32 + col) * 128 + kb * 16 + g * 8);
            #pragma unroll
            for (int s = 0; s < 2; ++s) {
                const int row = (ntb + s) * 32 + col + dk;
                const _Float16* bp = p2T + row * P2T_STRIDE + g * 8;
                #pragma unroll
                for (int kb = 0; kb < 8; ++kb) {
                    half8 B = *(const half8*)(bp + kb * 16);
                    acc[0][s] = __builtin_amdgcn_mfma_f32_32x32x16_f16(A[0][kb], B, acc[0][s], 0, 0, 0);
                    acc[1][s] = __builtin_amdgcn_mfma_f32_32x32x16_f16(A[1][kb], B, acc[1][s], 0, 0, 0);
                }
            }
        }
        // relu + pool(xor1, duplicated) + row-sum(DPP) -> 4 partials per channel
        // scr2 aliases p1T (dead after conv2; barrier above guarantees visibility order)
        const int q = wg * 2 + ((lane >> 4) & 1);
        #pragma unroll
        for (int mt = 0; mt < 2; ++mt) {
            float red[16];
            #pragma unroll
            for (int r = 0; r < 16; ++r) {
                float sum = 0.f;
                #pragma unroll
                for (int s = 0; s < 2; ++s) {
                    float v = fmaxf(acc[mt][s][r], 0.f);
                    sum += fmaxf(v, __shfl_xor(v, 1));
                }
                red[r] = dpp_rowsum16(sum);
            }
            if ((lane & 15) == 15) {
                #pragma unroll
                for (int r = 0; r < 16; ++r) {
                    int ch = (mtb + mt) * 32 + (r & 3) + 8 * (r >> 2) + 4 * g;
                    lds[SCR2_OFF + ch * 4 + q] = red[r];
                }
            }
        }
    }
    __syncthreads();

    // ---- mean: 4 partials each count pooled values twice -> /128
    if (t < 256) {
        const float4 qv = *(const float4*)&lds[SCR2_OFF + t * 4];
        lds[SCR_OFF + t] = (qv.x + qv.y + qv.z + qv.w) * (1.f / 128.f);
    }
    __syncthreads();

    // ---- fc (256->128) + relu
    {
        for (int ow = 0; ow < 16; ++ow) {
            const int o = wave * 16 + ow;
            float s = 0.f;
            #pragma unroll
            for (int m = 0; m < 4; ++m) {
                int i = lane + 64 * m;
                s += fcw[o * 256 + i] * lds[SCR_OFF + i];
            }
            #pragma unroll
            for (int off = 32; off > 0; off >>= 1) s += __shfl_down(s, off);
            if (lane == 0) lds[SCR_OFF + 256 + o] = fmaxf(s + fcb[o], 0.f);
        }
    }
    __syncthreads();

    // ---- batchnorm -> z (f16); sq from the QUANTIZED z (true squared distance)
    if (t < 128) {
        float hv = lds[SCR_OFF + 256 + t];
        float zv = gamma_[t] * (hv - bnm[t]) * (1.f / sqrtf(bnv[t] + 1e-5f)) + beta_[t];
        _Float16 zq = (_Float16)zv;
        zh[(size_t)n * 128 + t] = zq;
        float zqf = (float)zq;
        lds[SCR_OFF + 384 + t] = zqf * zqf;
    }
    if (t == 0) uout[n] = (info[2 * n + 1] == 1) ? info[2 * n] : -1;
    __syncthreads();
    if (t < 64) {
        float s = lds[SCR_OFF + 384 + t] + lds[SCR_OFF + 384 + 64 + t];
        #pragma unroll
        for (int off = 32; off > 0; off >>= 1) s += __shfl_down(s, off);
        if (t == 0) sqout[n] = s;
    }
}

// ---- pairwise via f16 MFMA: 128x128 tile/block, 4 waves, each 64x64 quadrant
#define PW_STRIDE 136   // f16; 68 words == 4 mod 32 -> conflict-free b128
#define PW_LDS_BYTES (2 * 128 * PW_STRIDE * 2)

__global__ __launch_bounds__(256, 2)
void pairwise_mfma(const _Float16* __restrict__ zh, const float* __restrict__ sq,
                   const int* __restrict__ u, float* __restrict__ out)
{
    extern __shared__ float ldsf[];
    _Float16* at = (_Float16*)ldsf;                  // [128][136]
    _Float16* bt = at + 128 * PW_STRIDE;
    const int t = threadIdx.x;
    const int i0 = blockIdx.y * 128;
    const int j0 = blockIdx.x * 128;

    #pragma unroll
    for (int r4 = 0; r4 < 8; ++r4) {
        int idx = t + 256 * r4;            // 0..2047
        int row = idx >> 4, c8 = (idx & 15) * 8;
        *(half8*)(at + row * PW_STRIDE + c8) = *(const half8*)(zh + (size_t)(i0 + row) * 128 + c8);
        *(half8*)(bt + row * PW_STRIDE + c8) = *(const half8*)(zh + (size_t)(j0 + row) * 128 + c8);
    }
    __syncthreads();

    const int lane = t & 63, wave = t >> 6;
    const int g = lane >> 5, col = lane & 31;
    const int ib = (wave & 1) * 64, jb = (wave >> 1) * 64;

    half8 A[2][8];
    #pragma unroll
    for (int mt = 0; mt < 2; ++mt)
        #pragma unroll
        for (int kb = 0; kb < 8; ++kb)
            A[mt][kb] = *(const half8*)(at + (ib + mt * 32 + col) * PW_STRIDE + kb * 16 + g * 8);

    floatx16 acc[2][2];
    #pragma unroll
    for (int a = 0; a < 2; ++a)
        #pragma unroll
        for (int b = 0; b < 2; ++b)
            #pragma unroll
            for (int r = 0; r < 16; ++r) acc[a][b][r] = 0.f;

    #pragma unroll
    for (int nt = 0; nt < 2; ++nt)
        #pragma unroll
        for (int kb = 0; kb < 8; ++kb) {
            half8 B = *(const half8*)(bt + (jb + nt * 32 + col) * PW_STRIDE + kb * 16 + g * 8);
            acc[0][nt] = __builtin_amdgcn_mfma_f32_32x32x16_f16(A[0][kb], B, acc[0][nt], 0, 0, 0);
            acc[1][nt] = __builtin_amdgcn_mfma_f32_32x32x16_f16(A[1][kb], B, acc[1][nt], 0, 0, 0);
        }

    #pragma unroll
    for (int nt = 0; nt < 2; ++nt) {
        const int j = j0 + jb + nt * 32 + col;
        const float sqj = sq[j];
        const int uj = u[j];
        #pragma unroll
        for (int mt = 0; mt < 2; ++mt) {
            #pragma unroll
            for (int r = 0; r < 16; ++r) {
                const int i = i0 + ib + mt * 32 + (r & 3) + 8 * (r >> 2) + 4 * g;
                float res;
                if (i == j) {
                    res = 0.f;
                } else {
                    float d2 = sq[i] + sqj - 2.f * acc[mt][nt][r];
                    float d = sqrtf(fmaxf(d2, 0.f));
                    int ui = u[i];
                    res = (ui == uj && ui >= 0) ? d : fmaxf(1.f - d, 0.f);
                }
                out[(size_t)i * 4096 + j] = res;
            }
        }
    }
}

extern "C" void kernel_launch(void* const* d_in, const int* in_sizes, int n_in,
                              void* d_out, int out_size, void* d_ws, size_t ws_size,
                              hipStream_t stream)
{
    const float* samples = (const float*)d_in[0];
    const int*   info    = (const int*)d_in[1];
    const float* w1  = (const float*)d_in[2];
    const float* b1  = (const float*)d_in[3];
    const float* w2  = (const float*)d_in[4];
    const float* b2  = (const float*)d_in[5];
    const float* w3  = (const float*)d_in[6];
    const float* b3  = (const float*)d_in[7];
    const float* fcw = (const float*)d_in[8];
    const float* fcb = (const float*)d_in[9];
    const float* g   = (const float*)d_in[10];
    const float* be  = (const float*)d_in[11];
    const float* bm  = (const float*)d_in[12];
    const float* bv  = (const float*)d_in[13];
    float* out = (float*)d_out;

    // ws: zh f16 [4096*128] @0 (1 MB); sq f32 @1MB (16 KB); u int @1MB+16K (16 KB);
    //     w1p/w2p/w3p f16 @1MB+32K
    _Float16* zhws = (_Float16*)d_ws;
    float*    sqws = (float*)((char*)d_ws + (1 << 20));
    int*      uws  = (int*)((char*)d_ws + (1 << 20) + 16384);
    _Float16* wp   = (_Float16*)((char*)d_ws + (1 << 20) + 32768);
    _Float16* w1p = wp;               // 8192
    _Float16* w2p = wp + 8192;        // 40960
    _Float16* w3p = wp + 49152;       // 98304

    hipLaunchKernelGGL(prep_weights, dim3(576), dim3(256), 0, stream,
                       w1, w2, w3, w1p, w2p, w3p);

    hipLaunchKernelGGL(cnn_fused, dim3(NS), dim3(512),
                       LDS_MAIN_FLOATS * sizeof(float), stream,
                       samples, info, w1p, w2p, w3p, b1, b2, b3, fcw, fcb,
                       g, be, bm, bv, zhws, sqws, uws);

    hipLaunchKernelGGL(pairwise_mfma, dim3(32, 32), dim3(256),
                       PW_LDS_BYTES, stream,
                       zhws, sqws, uws, out);
}